// Round 4
// baseline (102.934 us; speedup 1.0000x reference)
//
#include <hip/hip_runtime.h>
#include <hip/hip_bf16.h>
#include <math.h>

#define B_ 32
#define O_ 2
#define N_ 4096
#define D_ 128
#define M_ (O_*N_)        // 8192

typedef __bf16 bf16x8 __attribute__((ext_vector_type(8)));
typedef float  f32x4  __attribute__((ext_vector_type(4)));

// RTN-even fp32 -> bf16
static __device__ __forceinline__ unsigned short f2bf(float f) {
    unsigned int u = __float_as_uint(f);
    u += 0x7fffu + ((u >> 16) & 1u);
    return (unsigned short)(u >> 16);
}

// ---------------------------------------------------------------------------
// K0: Wu fp32 -> bf16, pre-permuted into the MFMA fragment image:
// row e (256 B), ushort pos = ks*32 + (cc&3)*8 + (cc>>2)*4 for source chunk
// c = 8*ks + cc (4 consecutive k). A B-fragment (lane l, k-step ks) is then
// the contiguous 16 B at e*256 + ks*64 + (l>>4)*16.
// ---------------------------------------------------------------------------
__global__ __launch_bounds__(256) void k_prep(const float* __restrict__ Wu,
        unsigned short* __restrict__ wup) {
    int idx = blockIdx.x*256 + threadIdx.x;     // 8192 chunks: i*4096 + e*32 + c
    int i = idx >> 12, e = (idx >> 5) & 127, c = idx & 31;
    int ks = c >> 3, cc = c & 7;
    float4 v = *(const float4*)(Wu + ((size_t)(i*D_ + e))*D_ + c*4);
    ushort4 h;
    h.x = f2bf(v.x); h.y = f2bf(v.y); h.z = f2bf(v.z); h.w = f2bf(v.w);
    int pos = ks*32 + (cc&3)*8 + (cc>>2)*4;
    *(ushort4*)(wup + ((size_t)(i*D_ + e))*D_ + pos) = h;
}

// ---------------------------------------------------------------------------
// K1: cvec[b][i][e] = bu[i][e] + sum_d x[b,i,last[b,i],d] * Wv[i,e,d]
// ---------------------------------------------------------------------------
__global__ __launch_bounds__(128) void k_cvec(const float* __restrict__ x,
        const float* __restrict__ Wv, const float* __restrict__ bu,
        const int* __restrict__ last, float* __restrict__ cvec)
{
    int bi = blockIdx.x;
    int b = bi >> 1, i = bi & 1;
    int e = threadIdx.x;
    __shared__ float xl[D_];
    int ln = last[bi];
    const float* xrow = x + (((size_t)b*O_ + i)*N_ + ln)*D_;
    xl[e] = xrow[e];
    __syncthreads();
    const float* wv = Wv + ((size_t)i*D_ + e)*D_;
    float acc = bu[i*D_ + e];
    #pragma unroll 8
    for (int d = 0; d < D_; ++d) acc += xl[d]*wv[d];
    cvec[bi*D_ + e] = acc;
}

// ---------------------------------------------------------------------------
// K2: MFMA logits + per-wave tile stats.
// Block = 256 thr = 4 waves; 128 rows x 128 e. x tile staged in LDS
// (k-permuted + XOR-swizzled); Wu fragments read DIRECTLY from the
// pre-permuted global image (64 KB, L2-resident).
// tstats[bi][g*2+wavehalf] = (max, sumexp) over 64 logits, g = o*32+tile.
// ---------------------------------------------------------------------------
__global__ __launch_bounds__(256, 2) void k_logits_mfma(
        const float* __restrict__ x, const unsigned short* __restrict__ wup,
        const float* __restrict__ cvec, const float* __restrict__ We,
        float* __restrict__ logits, float* __restrict__ tstats)
{
    __shared__ unsigned char xsb[32768];
    __shared__ float red[256];

    int blk  = blockIdx.x;
    int tile = blk & 31;
    int o    = (blk >> 5) & 1;
    int b    = blk >> 6;
    int n0   = tile * 128;

    int t = threadIdx.x;
    int l = t & 63;
    int w = t >> 6;
    int wr = w >> 1, wc = w & 1;
    int l15 = l & 15, lq = l >> 4;

    const float* xbase = x + (((size_t)b*O_ + o)*N_ + n0)*D_;

    // ---- stage x tile: fp32 -> bf16, k-permute + XOR swizzle ----
    #pragma unroll
    for (int it = 0; it < 16; ++it) {
        int idx = it*256 + t;          // 4096 float4 chunks
        int row = idx >> 5;
        int c   = idx & 31;
        float4 v = *(const float4*)(xbase + row*D_ + c*4);
        ushort4 h;
        h.x = f2bf(v.x); h.y = f2bf(v.y); h.z = f2bf(v.z); h.w = f2bf(v.w);
        int ks = c >> 3, cc = c & 7;
        int off = (ks*64 + (cc&3)*16 + (cc>>2)*8) ^ ((row & 15) << 4);
        *(ushort4*)(xsb + row*256 + off) = h;
    }
    __syncthreads();

    // ---- A fragments into registers (reused for both i) ----
    bf16x8 Af[4][4];
    #pragma unroll
    for (int ks = 0; ks < 4; ++ks) {
        #pragma unroll
        for (int m = 0; m < 4; ++m) {
            int row = wr*64 + m*16 + l15;
            int off = (ks*64 + lq*16) ^ ((row & 15) << 4);
            uint4 u = *(const uint4*)(xsb + row*256 + off);
            Af[ks][m] = __builtin_bit_cast(bf16x8, u);
        }
    }

    f32x4 zero = {0.f, 0.f, 0.f, 0.f};

    #pragma unroll
    for (int i = 0; i < O_; ++i) {
        const unsigned short* wb = wup + (size_t)i*D_*D_;

        f32x4 acc[4][4];
        #pragma unroll
        for (int m = 0; m < 4; ++m)
            #pragma unroll
            for (int n = 0; n < 4; ++n)
                acc[m][n] = zero;

        #pragma unroll
        for (int ks = 0; ks < 4; ++ks) {
            bf16x8 Bf[4];
            #pragma unroll
            for (int n = 0; n < 4; ++n) {
                int e = wc*64 + n*16 + l15;
                uint4 u = *(const uint4*)(wb + e*D_ + ks*32 + lq*8);
                Bf[n] = __builtin_bit_cast(bf16x8, u);
            }
            #pragma unroll
            for (int m = 0; m < 4; ++m)
                #pragma unroll
                for (int n = 0; n < 4; ++n)
                    acc[m][n] = __builtin_amdgcn_mfma_f32_16x16x32_bf16(
                        Af[ks][m], Bf[n], acc[m][n], 0, 0, 0);
        }

        // ---- epilogue: sigmoid gate, dot We, reduce over e ----
        int bi = b*O_ + i;
        float cv[4], wev[4];
        #pragma unroll
        for (int n = 0; n < 4; ++n) {
            int e = wc*64 + n*16 + l15;
            cv[n]  = cvec[bi*D_ + e];
            wev[n] = We[i*D_ + e];
        }
        #pragma unroll
        for (int m = 0; m < 4; ++m) {
            float pv[4] = {0.f, 0.f, 0.f, 0.f};
            #pragma unroll
            for (int n = 0; n < 4; ++n) {
                #pragma unroll
                for (int r = 0; r < 4; ++r) {
                    float z = acc[m][n][r] + cv[n];
                    float s = __builtin_amdgcn_rcpf(1.f + __expf(-z));
                    pv[r] += s * wev[n];
                }
            }
            #pragma unroll
            for (int off = 1; off < 16; off <<= 1) {
                #pragma unroll
                for (int r = 0; r < 4; ++r)
                    pv[r] += __shfl_xor(pv[r], off);
            }
            if (l15 == 0) {
                int rb = wr*64 + m*16 + lq*4;
                #pragma unroll
                for (int r = 0; r < 4; ++r)
                    red[wc*128 + rb + r] = pv[r];
            }
        }
        __syncthreads();
        if (t < 128) {
            float lg = red[t] + red[128 + t];
            logits[(size_t)bi*M_ + o*N_ + n0 + t] = lg;
            // per-wave (64-logit) stats
            float mx = lg;
            #pragma unroll
            for (int off = 1; off < 64; off <<= 1) mx = fmaxf(mx, __shfl_xor(mx, off));
            float sm = __expf(lg - mx);
            #pragma unroll
            for (int off = 1; off < 64; off <<= 1) sm += __shfl_xor(sm, off);
            if ((t & 63) == 0) {
                int g = o*32 + tile;
                int j = g*2 + (t >> 6);
                tstats[(size_t)bi*256 + j*2]     = mx;
                tstats[(size_t)bi*256 + j*2 + 1] = sm;
            }
        }
        __syncthreads();
    }
}

// ---------------------------------------------------------------------------
// K3: stats finalize (from 128 per-wave tile stats) + weighted partial sums.
// grid = bi*16 + chunk (1024 blocks, 256 thr). chunk = 512 consecutive m.
// ---------------------------------------------------------------------------
__global__ __launch_bounds__(256) void k_wsum(const float* __restrict__ logits,
        const float* __restrict__ tstats, const float* __restrict__ x,
        float* __restrict__ part)
{
    int blk = blockIdx.x;
    int chunk = blk & 15;
    int bi = blk >> 4;
    int b = bi >> 1;
    int t = threadIdx.x;
    int lane = t & 63, w = t >> 6;

    __shared__ float wbuf[512];
    __shared__ float pacc[8][128];
    __shared__ float sred[8];

    // ---- phase A: global stats from 128 (max,sum) pairs ----
    const float* ts = tstats + (size_t)bi*256;
    float my_m = (t < 128) ? ts[t*2]     : -1e30f;
    float my_s = (t < 128) ? ts[t*2 + 1] : 0.f;
    float m = my_m;
    #pragma unroll
    for (int off = 1; off < 64; off <<= 1) m = fmaxf(m, __shfl_xor(m, off));
    if (lane == 0) sred[w] = m;
    __syncthreads();
    m = fmaxf(fmaxf(sred[0], sred[1]), fmaxf(sred[2], sred[3]));
    float c = (t < 128) ? my_s*__expf(my_m - m) : 0.f;
    #pragma unroll
    for (int off = 1; off < 64; off <<= 1) c += __shfl_xor(c, off);
    if (lane == 0) sred[4 + w] = c;
    __syncthreads();
    float inv = 1.f/(sred[4] + sred[5] + sred[6] + sred[7]);

    // ---- phase B: 512 weights into LDS ----
    int m0 = chunk*512;
    const float* lg = logits + (size_t)bi*M_ + m0;
    wbuf[t]       = __expf(lg[t]       - m)*inv;
    wbuf[t + 256] = __expf(lg[t + 256] - m)*inv;
    __syncthreads();

    // ---- phase C: float4 weighted sum, 8 row-stripes x 32 d4 ----
    int d4 = t & 31, s = t >> 5;
    f32x4 a = {0.f, 0.f, 0.f, 0.f};
    const float* xb = x + ((size_t)b*M_ + m0)*D_ + d4*4;
    #pragma unroll 8
    for (int r = 0; r < 64; ++r) {
        int row = s*64 + r;
        float wgt = wbuf[row];
        f32x4 xv = *(const f32x4*)(xb + (size_t)row*D_);
        a += wgt*xv;
    }
    #pragma unroll
    for (int j = 0; j < 4; ++j) pacc[s][d4*4 + j] = a[j];
    __syncthreads();
    if (t < 128) {
        float acc = 0.f;
        #pragma unroll
        for (int st = 0; st < 8; ++st) acc += pacc[st][t];
        part[(size_t)blk*D_ + t] = acc;
    }
}

// ---------------------------------------------------------------------------
// K4: deterministic reduction of the 16 chunks per (b,i)
// ---------------------------------------------------------------------------
__global__ __launch_bounds__(128) void k_red(const float* __restrict__ part,
        float* __restrict__ out)
{
    int bi = blockIdx.x, t = threadIdx.x;
    float s = 0.f;
    #pragma unroll
    for (int c = 0; c < 16; ++c) s += part[(size_t)(bi*16 + c)*D_ + t];
    out[bi*D_ + t] = s;
}

extern "C" void kernel_launch(void* const* d_in, const int* in_sizes, int n_in,
                              void* d_out, int out_size, void* d_ws, size_t ws_size,
                              hipStream_t stream) {
    const float* x    = (const float*)d_in[0];
    const float* Wu   = (const float*)d_in[1];
    const float* bu   = (const float*)d_in[2];
    const float* Wv   = (const float*)d_in[3];
    const float* We   = (const float*)d_in[4];
    const int*   last = (const int*)d_in[5];
    float* out = (float*)d_out;

    // workspace layout (floats)
    float* ws      = (float*)d_ws;
    float* logits  = ws;                                  // 524288
    float* cvec    = logits + (size_t)B_*O_*M_;           // 8192
    float* tstats  = cvec + B_*O_*D_;                     // 16384
    float* part    = tstats + (size_t)B_*O_*256;          // 131072
    unsigned short* wup = (unsigned short*)(part + (size_t)B_*O_*16*D_); // 32768 bf16

    k_prep       <<<32, 256, 0, stream>>>(Wu, wup);
    k_cvec       <<<B_*O_, 128, 0, stream>>>(x, Wv, bu, last, cvec);
    k_logits_mfma<<<B_*O_*(N_/128), 256, 0, stream>>>(x, wup, cvec, We, logits, tstats);
    k_wsum       <<<B_*O_*(M_/512), 256, 0, stream>>>(logits, tstats, x, part);
    k_red        <<<B_*O_, 128, 0, stream>>>(part, out);
}